// Round 7
// baseline (233.430 us; speedup 1.0000x reference)
//
#include <hip/hip_runtime.h>

#define N_PARTS 62
#define M_SAMP  512
#define D_DIM   256
#define MARGIN  0.2f

typedef unsigned short ushort_t;
typedef __attribute__((ext_vector_type(8))) short bf16x8;   // 8 bf16 = 4 VGPRs
typedef __attribute__((ext_vector_type(4))) float f32x4;

__device__ __forceinline__ ushort_t bf16_rne(float f) {
    unsigned u = __float_as_uint(f);
    unsigned r = u + 0x7fffu + ((u >> 16) & 1u);
    return (ushort_t)(r >> 16);
}

// K0: zero d_out (124 floats) so K1 blocks can merge with atomicAdd.
__global__ void zero_out_kernel(float* __restrict__ out) {
    if (threadIdx.x < 2 * N_PARTS) out[threadIdx.x] = 0.0f;
}

// K1: EVERYTHING in one kernel — no workspace, no prep round-trip.
// Grid 512 blocks (id = rt*64 + n; XCD = id%8 = n%8 so all 8 row-blocks of a
// part share one XCD's L2 for the 8x re-read of its fp32 rows). Block =
// 512 thr / 8 waves = 64 rows x all 512 cols; wave w owns col-slab [w*64,w*64+64).
// Per 32-k chunk: threads read fp32 from d_in, convert bf16 in registers,
// ds_write_b128 into a swizzled LDS tile (rows 0..511 — the A-slab is a subset,
// so no separate A staging). sq accumulated in registers during conversion.
// Double-buffered, ONE barrier per chunk.
__global__ __launch_bounds__(512, 4) void fused_all_kernel(const float* __restrict__ feat,
                                                           float* __restrict__ out) {
    const int id = blockIdx.x;
    const int n  = id & 63;          // part  (XCD affinity: id % 8 == n % 8)
    const int rt = id >> 6;          // row-slab
    if (n >= N_PARTS) return;
    const int r0 = rt * 64;
    const int tid = threadIdx.x;
    const int wave = tid >> 6, lane = tid & 63;
    const float* Fin = feat + (size_t)n * (M_SAMP * D_DIM);

    // [512 rows][32 k] bf16 (32 KB each). Physical 16B-slot s of row r holds
    // logical k-quad q = s ^ ((r>>1)&3): balanced banks for both the b128
    // staging writes and the b128 fragment reads.
    __shared__ alignas(16) ushort_t bb0[M_SAMP * 32];
    __shared__ alignas(16) ushort_t bb1[M_SAMP * 32];
    __shared__ float sq_lds[M_SAMP];
    __shared__ float mrg[8][64][3];

    f32x4 acc[4][4] = {};
    float sqacc[4] = {0.f, 0.f, 0.f, 0.f};   // per-thread partial row sum-of-squares

    const int sq_q = tid & 3;    // k-quad (8 floats) this thread converts
    const int sr_b = tid >> 2;   // row (mod 128)

    // Convert+stage chunk c (k = c*32..c*32+31) into LDS tile bb.
    auto stage = [&](int c, ushort_t* bb) {
        #pragma unroll
        for (int p = 0; p < 4; ++p) {
            const int r = p * 128 + sr_b;
            const float* src = Fin + (size_t)r * D_DIM + c * 32 + sq_q * 8;
            const float4 v0 = ((const float4*)src)[0];
            const float4 v1 = ((const float4*)src)[1];
            const float f[8] = {v0.x, v0.y, v0.z, v0.w, v1.x, v1.y, v1.z, v1.w};
            bf16x8 w;
            float s = 0.f;
            #pragma unroll
            for (int i = 0; i < 8; ++i) {
                const ushort_t u = bf16_rne(f[i]);
                const float fr = __uint_as_float((unsigned)u << 16);
                s += fr * fr;                 // sq of the ROUNDED value
                w[i] = (short)u;
            }
            sqacc[p] += s;
            const int slot = sq_q ^ ((r >> 1) & 3);
            *(bf16x8*)(bb + r * 32 + slot * 8) = w;   // ds_write_b128
        }
    };

    auto compute = [&](const ushort_t* bb) {
        bf16x8 bfr[4];
        #pragma unroll
        for (int ni = 0; ni < 4; ++ni) {
            const int rb = wave * 64 + ni * 16 + (lane & 15);
            const int sb = (lane >> 4) ^ ((rb >> 1) & 3);
            bfr[ni] = *(const bf16x8*)(bb + rb * 32 + sb * 8);
        }
        #pragma unroll
        for (int mi = 0; mi < 4; ++mi) {
            const int ra = r0 + mi * 16 + (lane & 15);
            const int sa = (lane >> 4) ^ ((ra >> 1) & 3);
            const bf16x8 af = *(const bf16x8*)(bb + ra * 32 + sa * 8);
            #pragma unroll
            for (int ni = 0; ni < 4; ++ni)
                acc[mi][ni] = __builtin_amdgcn_mfma_f32_16x16x32_bf16(
                    af, bfr[ni], acc[mi][ni], 0, 0, 0);
        }
    };

    stage(0, bb0);
    __syncthreads();
    #pragma unroll
    for (int cc = 0; cc < 8; cc += 2) {
        stage(cc + 1, bb1);   // writes bb1 while everyone reads bb0 — no race
        compute(bb0);
        __syncthreads();      // done reading bb0 / writing bb1
        if (cc + 2 < 8) stage(cc + 2, bb0);
        compute(bb1);
        __syncthreads();
    }

    // Fold per-thread sq partials: 4 lanes (k-quads) per row, 2 shuffles.
    #pragma unroll
    for (int p = 0; p < 4; ++p) {
        float s = sqacc[p];
        s += __shfl_xor(s, 1);
        s += __shfl_xor(s, 2);
        if ((lane & 3) == 0) sq_lds[p * 128 + sr_b] = s;
    }
    __syncthreads();

    // Epilogue: dist + hard-pos/neg + row sums. C/D layout: col=lane&15,
    // row=(lane>>4)*4+reg (m89-verified; identical to R2-R6 which passed).
    float sqc[4];
    #pragma unroll
    for (int ni = 0; ni < 4; ++ni)
        sqc[ni] = sq_lds[wave * 64 + ni * 16 + (lane & 15)];
    #pragma unroll
    for (int mi = 0; mi < 4; ++mi) {
        #pragma unroll
        for (int p = 0; p < 4; ++p) {
            const int rl = mi * 16 + (lane >> 4) * 4 + p;   // block-local row
            const int R  = r0 + rl;                          // part-local row
            const float sr = sq_lds[R];
            float ds = 0.f, hp = 0.f, hn = 1e30f;
            #pragma unroll
            for (int ni = 0; ni < 4; ++ni) {
                const int C = wave * 64 + ni * 16 + (lane & 15);
                const float d2 = sr + sqc[ni] - 2.f * acc[mi][ni][p];
                const float d  = sqrtf(fmaxf(d2, 0.f));
                ds += d;
                if ((R >> 3) == (C >> 3)) hp = fmaxf(hp, d);   // label = m>>3
                else                      hn = fminf(hn, d);
            }
            #pragma unroll
            for (int off = 1; off < 16; off <<= 1) {
                ds += __shfl_xor(ds, off);
                hp = fmaxf(hp, __shfl_xor(hp, off));
                hn = fminf(hn, __shfl_xor(hn, off));
            }
            if ((lane & 15) == 0) {
                mrg[wave][rl][0] = hp;
                mrg[wave][rl][1] = hn;
                mrg[wave][rl][2] = ds;
            }
        }
    }
    __syncthreads();
    if (tid < 64) {   // one lane per row: merge the 8 col-slabs + final sum
        float hp = 0.f, hn = 1e30f, bd = 0.f;
        #pragma unroll
        for (int w = 0; w < 8; ++w) {
            hp = fmaxf(hp, mrg[w][tid][0]);
            hn = fminf(hn, mrg[w][tid][1]);
            bd += mrg[w][tid][2];
        }
        float bl = fmaxf(MARGIN + hp - hn, 0.f);
        #pragma unroll
        for (int off = 32; off > 0; off >>= 1) {
            bl += __shfl_xor(bl, off);
            bd += __shfl_xor(bd, off);
        }
        if (lane == 0) {
            atomicAdd(&out[n],           bl * (1.0f / 512.0f));
            atomicAdd(&out[N_PARTS + n], bd * (1.0f / (512.0f * 512.0f)));
        }
    }
}

extern "C" void kernel_launch(void* const* d_in, const int* in_sizes, int n_in,
                              void* d_out, int out_size, void* d_ws, size_t ws_size,
                              hipStream_t stream) {
    const float* feat = (const float*)d_in[0];    // [62, 512, 256] fp32
    float* out = (float*)d_out;                   // [124]
    zero_out_kernel<<<dim3(1), 128, 0, stream>>>(out);
    fused_all_kernel<<<dim3(512), 512, 0, stream>>>(feat, out);
}

// Round 8
// 99.503 us; speedup vs baseline: 2.3460x; 2.3460x over previous
//
#include <hip/hip_runtime.h>

#define N_PARTS 62
#define M_SAMP  512
#define D_DIM   256
#define MARGIN  0.2f
#define ROWS    (N_PARTS * M_SAMP)   // 31744
#define PART_ELEMS (M_SAMP * D_DIM)  // 131072 bf16 per part

typedef unsigned short ushort_t;
typedef __attribute__((ext_vector_type(8))) short bf16x8;   // 8 bf16 = 4 VGPRs
typedef __attribute__((ext_vector_type(4))) float f32x4;

__device__ __forceinline__ ushort_t bf16_rne(float f) {
    unsigned u = __float_as_uint(f);
    unsigned r = u + 0x7fffu + ((u >> 16) & 1u);
    return (ushort_t)(r >> 16);
}

// K1: fp32 -> bf16 (RNE), per-row sum-of-squares of the ROUNDED values,
// zero-init d_out. Output is FRAGMENT-MAJOR: per (part, chunk c=k>>5,
// row-group g=row>>4) a contiguous 1 KB frag block; within it lane l holds
//   F[g*16 + (l&15)][c*32 + (l>>4)*8 .. +7]
// = exactly the logical MFMA frag the old LDS path delivered. Fused can then
// load frags global->VGPR at base + lane*16 with no LDS and no barriers.
__global__ __launch_bounds__(256) void prep_kernel(const float* __restrict__ feat,
                                                   ushort_t* __restrict__ Fb,
                                                   float* __restrict__ sq,
                                                   float* __restrict__ out) {
    const int gid  = blockIdx.x * 256 + threadIdx.x;
    const int lane = threadIdx.x & 63;
    const int row  = gid >> 6;                    // one wave per row
    const int part = row >> 9, rp = row & 511;
    const float4 v = ((const float4*)(feat + (size_t)row * D_DIM))[lane];
    ushort4 us;
    us.x = bf16_rne(v.x); us.y = bf16_rne(v.y);
    us.z = bf16_rne(v.z); us.w = bf16_rne(v.w);
    const float fx = __uint_as_float((unsigned)us.x << 16);
    const float fy = __uint_as_float((unsigned)us.y << 16);
    const float fz = __uint_as_float((unsigned)us.z << 16);
    const float fw = __uint_as_float((unsigned)us.w << 16);
    // lane covers k = lane*4 .. +3: c = lane>>3, quad = (lane>>1)&3, i0 = (lane&1)*4
    const int c  = lane >> 3;
    const int q  = (lane >> 1) & 3;
    const int g  = rp >> 4;
    const int fl = (rp & 15) | (q << 4);          // frag lane
    *(ushort4*)(Fb + (size_t)part * PART_ELEMS + ((size_t)(c * 32 + g) * 512)
                + fl * 8 + (lane & 1) * 4) = us;
    float ssum = fx * fx + fy * fy + fz * fz + fw * fw;
    #pragma unroll
    for (int off = 32; off > 0; off >>= 1) ssum += __shfl_xor(ssum, off);
    if (lane == 0) sq[row] = ssum;
    if (gid < 2 * N_PARTS) out[gid] = 0.0f;
}

// K2: LDS-free MFMA K-loop. Grid 512 (id = rt*64 + n -> XCD = n%8: all 8
// row-blocks of a part share one XCD's L2; ~8 parts x 256 KB bf16 = 2 MB/XCD).
// Block = 512 thr / 8 waves = 64 rows x all 512 cols; wave w owns cols
// [w*64, w*64+64) (acc[4][4]). Frags loaded straight global->VGPR
// (global_load_dwordx4, lane-contiguous). ZERO barriers until the epilogue.
__global__ __launch_bounds__(512, 4) void fused_triplet_kernel(const ushort_t* __restrict__ Fb,
                                                               const float* __restrict__ sq,
                                                               float* __restrict__ out) {
    const int id = blockIdx.x;
    const int n  = id & 63;          // part (XCD affinity: id%8 == n%8)
    const int rt = id >> 6;          // row-slab
    if (n >= N_PARTS) return;
    const int r0 = rt * 64;
    const int tid = threadIdx.x;
    const int wave = tid >> 6, lane = tid & 63;
    const ushort_t* F = Fb + (size_t)n * PART_ELEMS;
    const float* SQ = sq + n * M_SAMP;

    __shared__ float mrg[8][64][3];   // per-wave row stats (6 KB only)

    f32x4 acc[4][4] = {};

    #pragma unroll 2
    for (int c = 0; c < 8; ++c) {
        const ushort_t* base = F + (size_t)c * (32 * 512);
        bf16x8 af[4], bf[4];
        #pragma unroll
        for (int mi = 0; mi < 4; ++mi)
            af[mi] = *(const bf16x8*)(base + (size_t)(rt * 4 + mi) * 512 + lane * 8);
        #pragma unroll
        for (int ni = 0; ni < 4; ++ni)
            bf[ni] = *(const bf16x8*)(base + (size_t)(wave * 4 + ni) * 512 + lane * 8);
        #pragma unroll
        for (int mi = 0; mi < 4; ++mi)
            #pragma unroll
            for (int ni = 0; ni < 4; ++ni)
                acc[mi][ni] = __builtin_amdgcn_mfma_f32_16x16x32_bf16(
                    af[mi], bf[ni], acc[mi][ni], 0, 0, 0);
    }

    // Epilogue: dist + hard-pos/neg + row sums. C/D layout: col=lane&15,
    // row=(lane>>4)*4+reg (verified across R2-R7 passes).
    float sqc[4];
    #pragma unroll
    for (int ni = 0; ni < 4; ++ni)
        sqc[ni] = SQ[wave * 64 + ni * 16 + (lane & 15)];
    #pragma unroll
    for (int mi = 0; mi < 4; ++mi) {
        #pragma unroll
        for (int p = 0; p < 4; ++p) {
            const int rl = mi * 16 + (lane >> 4) * 4 + p;   // block-local row
            const int R  = r0 + rl;                          // part-local row
            const float sr = SQ[R];
            float ds = 0.f, hp = 0.f, hn = 1e30f;
            #pragma unroll
            for (int ni = 0; ni < 4; ++ni) {
                const int C = wave * 64 + ni * 16 + (lane & 15);
                const float d2 = sr + sqc[ni] - 2.f * acc[mi][ni][p];
                const float d  = sqrtf(fmaxf(d2, 0.f));
                ds += d;
                if ((R >> 3) == (C >> 3)) hp = fmaxf(hp, d);   // label = m>>3
                else                      hn = fminf(hn, d);
            }
            #pragma unroll
            for (int off = 1; off < 16; off <<= 1) {
                ds += __shfl_xor(ds, off);
                hp = fmaxf(hp, __shfl_xor(hp, off));
                hn = fminf(hn, __shfl_xor(hn, off));
            }
            if ((lane & 15) == 0) {
                mrg[wave][rl][0] = hp;
                mrg[wave][rl][1] = hn;
                mrg[wave][rl][2] = ds;
            }
        }
    }
    __syncthreads();
    if (tid < 64) {   // one lane per row: merge the 8 col-slabs + final sum
        float hp = 0.f, hn = 1e30f, bd = 0.f;
        #pragma unroll
        for (int w = 0; w < 8; ++w) {
            hp = fmaxf(hp, mrg[w][tid][0]);
            hn = fminf(hn, mrg[w][tid][1]);
            bd += mrg[w][tid][2];
        }
        float bl = fmaxf(MARGIN + hp - hn, 0.f);
        #pragma unroll
        for (int off = 32; off > 0; off >>= 1) {
            bl += __shfl_xor(bl, off);
            bd += __shfl_xor(bd, off);
        }
        if (lane == 0) {
            atomicAdd(&out[n],           bl * (1.0f / 512.0f));
            atomicAdd(&out[N_PARTS + n], bd * (1.0f / (512.0f * 512.0f)));
        }
    }
}

extern "C" void kernel_launch(void* const* d_in, const int* in_sizes, int n_in,
                              void* d_out, int out_size, void* d_ws, size_t ws_size,
                              hipStream_t stream) {
    const float* feat = (const float*)d_in[0];    // [62, 512, 256] fp32
    float* out = (float*)d_out;                   // [124]

    ushort_t* Fb = (ushort_t*)d_ws;                                   // frag-major bf16
    float* sq    = (float*)((char*)d_ws + (size_t)ROWS * D_DIM * 2);  // row sum-of-squares

    prep_kernel<<<dim3(ROWS / 4), 256, 0, stream>>>(feat, Fb, sq, out);
    fused_triplet_kernel<<<dim3(512), 512, 0, stream>>>(Fb, sq, out);
}